// Round 1
// baseline (58.419 us; speedup 1.0000x reference)
//
#include <hip/hip_runtime.h>

// Shapes (fixed by setup_inputs):
//   zs   (128,256,1024) f32     rzs (128,256,1024) f32
//   pts  (128,256,118,2) f32    best (128,118,2) f32
//   qy   (128,256,64) f32       gts (128,128,118,2) f32
//   best_gt (128,118,2) f32     mapping (128,128) i32
//   vector_dims scalar = 64

namespace {
constexpr int NA4 = 128 * 256 * 64 / 4;    // qy float4 count   = 524288
constexpr int NB4 = 128 * 128 * 1024 / 4;  // ae float4 count   = 4194304
constexpr int NC2 = 128 * 128 * 118;       // bias float2 count = 1933312
constexpr int ND2 = 128 * 118;             // best float2 count = 15104
}

__global__ __launch_bounds__(256) void fused_loss(
    const float* __restrict__ zs, const float* __restrict__ rzs,
    const float* __restrict__ pts, const float* __restrict__ best,
    const float* __restrict__ qy, const float* __restrict__ gts,
    const float* __restrict__ best_gt, const int* __restrict__ mapping,
    double* __restrict__ acc)
{
    const int tid = blockIdx.x * blockDim.x + threadIdx.x;
    const int stride = gridDim.x * blockDim.x;
    const float logV = 4.1588830833596715f;  // log(64)

    double accA = 0.0, accB = 0.0, accC = 0.0, accCm = 0.0, accD = 0.0, accDm = 0.0;

    // ---- Segment A: KLD over qy: sum qy*(log(qy+eps)+log V) ----
    const float4* qy4 = reinterpret_cast<const float4*>(qy);
    for (int idx = tid; idx < NA4; idx += stride) {
        float4 q = qy4[idx];
        float s = q.x * (logf(q.x + 1e-20f) + logV)
                + q.y * (logf(q.y + 1e-20f) + logV)
                + q.z * (logf(q.z + 1e-20f) + logV)
                + q.w * (logf(q.w + 1e-20f) + logV);
        accA += (double)s;
    }

    // ---- Segment B: ae = mse(rzs[b,map[b,i],:], zs[b,i,:]) ----
    const float4* rzs4 = reinterpret_cast<const float4*>(rzs);
    const float4* zs4  = reinterpret_cast<const float4*>(zs);
    for (int idx = tid; idx < NB4; idx += stride) {
        int off = idx & 255;        // float4 offset within D=1024 row
        int row = idx >> 8;         // b*128 + i
        int b   = row >> 7;
        int i   = row & 127;
        int m   = mapping[row];
        float4 r = rzs4[(((b << 8) + m) << 8) + off];
        float4 z = zs4 [(((b << 8) + i) << 8) + off];
        float dx = r.x - z.x, dy = r.y - z.y, dz = r.z - z.z, dw = r.w - z.w;
        accB += (double)(dx * dx + dy * dy + dz * dz + dw * dw);
    }

    // ---- Segment C: bias = mse(pts[b,map[b,i]], gts[b,i]) + marked ----
    const float2* pts2 = reinterpret_cast<const float2*>(pts);
    const float2* gts2 = reinterpret_cast<const float2*>(gts);
    for (int idx = tid; idx < NC2; idx += stride) {
        unsigned row = (unsigned)idx / 118u;   // b*128 + i
        int p = idx - (int)row * 118;
        int b = (int)(row >> 7);
        int m = mapping[row];
        float2 pt = pts2[((b << 8) + m) * 118 + p];
        float2 g  = gts2[(int)row * 118 + p];
        float dx = pt.x - g.x, dy = pt.y - g.y;
        float sq = dx * dx + dy * dy;
        accC += (double)sq;
        if (p == 0 || p == 29 || p == 88 || p == 117) accCm += (double)sq;
    }

    // ---- Segment D: best mse + marked ----
    const float2* best2 = reinterpret_cast<const float2*>(best);
    const float2* bgt2  = reinterpret_cast<const float2*>(best_gt);
    for (int idx = tid; idx < ND2; idx += stride) {
        unsigned bi = (unsigned)idx / 118u;
        int p = idx - (int)bi * 118;
        float2 pb = best2[idx];
        float2 g  = bgt2[idx];
        float dx = pb.x - g.x, dy = pb.y - g.y;
        float sq = dx * dx + dy * dy;
        accD += (double)sq;
        if (p == 0 || p == 29 || p == 88 || p == 117) accDm += (double)sq;
    }

    // weights: kld 1/(B*S), ae 1/(B*Sg*D), bias 1/(B*Sg*P*2) + 10/(B*Sg*8),
    //          best 1/(B*P*2) + 10/(B*8)
    double total = accA  * (1.0 / 32768.0)
                 + accB  * (1.0 / 16777216.0)
                 + accC  * (1.0 / 3866624.0)
                 + accCm * (10.0 / 131072.0)
                 + accD  * (1.0 / 30208.0)
                 + accDm * (10.0 / 1024.0);

    // ---- block reduce (wave shfl + LDS) ----
    for (int off = 32; off > 0; off >>= 1)
        total += __shfl_down(total, off, 64);
    __shared__ double wsum[4];
    int lane = threadIdx.x & 63;
    int wid  = threadIdx.x >> 6;
    if (lane == 0) wsum[wid] = total;
    __syncthreads();
    if (threadIdx.x == 0) {
        double t = wsum[0] + wsum[1] + wsum[2] + wsum[3];
        atomicAdd(acc, t);
    }
}

__global__ void finalize(const double* __restrict__ acc, float* __restrict__ out)
{
    out[0] = (float)acc[0];
}

extern "C" void kernel_launch(void* const* d_in, const int* in_sizes, int n_in,
                              void* d_out, int out_size, void* d_ws, size_t ws_size,
                              hipStream_t stream) {
    const float* zs      = (const float*)d_in[0];
    const float* rzs     = (const float*)d_in[1];
    const float* pts     = (const float*)d_in[2];
    const float* best    = (const float*)d_in[3];
    const float* qy      = (const float*)d_in[4];
    const float* gts     = (const float*)d_in[5];
    const float* best_gt = (const float*)d_in[6];
    const int*   mapping = (const int*)d_in[7];

    double* acc = (double*)d_ws;
    hipMemsetAsync(d_ws, 0, sizeof(double), stream);

    fused_loss<<<2048, 256, 0, stream>>>(zs, rzs, pts, best, qy, gts, best_gt,
                                         mapping, acc);
    finalize<<<1, 1, 0, stream>>>(acc, (float*)d_out);
}

// Round 2
// 34.227 us; speedup vs baseline: 1.7068x; 1.7068x over previous
//
#include <hip/hip_runtime.h>

// Shapes (fixed by setup_inputs):
//   zs   (128,256,1024) f32     rzs (128,256,1024) f32
//   pts  (128,256,118,2) f32    best (128,118,2) f32
//   qy   (128,256,64) f32       gts (128,128,118,2) f32
//   best_gt (128,118,2) f32     mapping (128,128) i32
//   vector_dims scalar = 64

namespace {
constexpr int NBLOCKS = 2048;
constexpr int NA4 = 128 * 256 * 64 / 4;    // qy float4 count   = 524288
constexpr int NB4 = 128 * 128 * 1024 / 4;  // ae float4 count   = 4194304
constexpr int NC2 = 128 * 128 * 118;       // bias float2 count = 1933312
constexpr int ND2 = 128 * 118;             // best float2 count = 15104
}

__global__ __launch_bounds__(256) void fused_loss(
    const float* __restrict__ zs, const float* __restrict__ rzs,
    const float* __restrict__ pts, const float* __restrict__ best,
    const float* __restrict__ qy, const float* __restrict__ gts,
    const float* __restrict__ best_gt, const int* __restrict__ mapping,
    double* __restrict__ partials)
{
    const int tid = blockIdx.x * blockDim.x + threadIdx.x;
    const int stride = gridDim.x * blockDim.x;
    const float logV = 4.1588830833596715f;  // log(64)

    double accA = 0.0, accB = 0.0, accC = 0.0, accCm = 0.0, accD = 0.0, accDm = 0.0;

    // ---- Segment A: KLD over qy: sum qy*(log(qy+eps)+log V) ----
    const float4* qy4 = reinterpret_cast<const float4*>(qy);
    for (int idx = tid; idx < NA4; idx += stride) {
        float4 q = qy4[idx];
        float s = q.x * (logf(q.x + 1e-20f) + logV)
                + q.y * (logf(q.y + 1e-20f) + logV)
                + q.z * (logf(q.z + 1e-20f) + logV)
                + q.w * (logf(q.w + 1e-20f) + logV);
        accA += (double)s;
    }

    // ---- Segment B: ae = mse(rzs[b,map[b,i],:], zs[b,i,:]) ----
    const float4* rzs4 = reinterpret_cast<const float4*>(rzs);
    const float4* zs4  = reinterpret_cast<const float4*>(zs);
    for (int idx = tid; idx < NB4; idx += stride) {
        int off = idx & 255;        // float4 offset within D=1024 row
        int row = idx >> 8;         // b*128 + i
        int b   = row >> 7;
        int i   = row & 127;
        int m   = mapping[row];
        float4 r = rzs4[(((b << 8) + m) << 8) + off];
        float4 z = zs4 [(((b << 8) + i) << 8) + off];
        float dx = r.x - z.x, dy = r.y - z.y, dz = r.z - z.z, dw = r.w - z.w;
        accB += (double)(dx * dx + dy * dy + dz * dz + dw * dw);
    }

    // ---- Segment C: bias = mse(pts[b,map[b,i]], gts[b,i]) + marked ----
    const float2* pts2 = reinterpret_cast<const float2*>(pts);
    const float2* gts2 = reinterpret_cast<const float2*>(gts);
    for (int idx = tid; idx < NC2; idx += stride) {
        unsigned row = (unsigned)idx / 118u;   // b*128 + i
        int p = idx - (int)row * 118;
        int b = (int)(row >> 7);
        int m = mapping[row];
        float2 pt = pts2[((b << 8) + m) * 118 + p];
        float2 g  = gts2[(int)row * 118 + p];
        float dx = pt.x - g.x, dy = pt.y - g.y;
        float sq = dx * dx + dy * dy;
        accC += (double)sq;
        if (p == 0 || p == 29 || p == 88 || p == 117) accCm += (double)sq;
    }

    // ---- Segment D: best mse + marked ----
    const float2* best2 = reinterpret_cast<const float2*>(best);
    const float2* bgt2  = reinterpret_cast<const float2*>(best_gt);
    for (int idx = tid; idx < ND2; idx += stride) {
        unsigned bi = (unsigned)idx / 118u;
        int p = idx - (int)bi * 118;
        float2 pb = best2[idx];
        float2 g  = bgt2[idx];
        float dx = pb.x - g.x, dy = pb.y - g.y;
        float sq = dx * dx + dy * dy;
        accD += (double)sq;
        if (p == 0 || p == 29 || p == 88 || p == 117) accDm += (double)sq;
    }

    // weights: kld 1/(B*S), ae 1/(B*Sg*D), bias 1/(B*Sg*P*2) + 10/(B*Sg*8),
    //          best 1/(B*P*2) + 10/(B*8)
    double total = accA  * (1.0 / 32768.0)
                 + accB  * (1.0 / 16777216.0)
                 + accC  * (1.0 / 3866624.0)
                 + accCm * (10.0 / 131072.0)
                 + accD  * (1.0 / 30208.0)
                 + accDm * (10.0 / 1024.0);

    // ---- block reduce (wave shfl + LDS), then ONE store per block ----
    for (int off = 32; off > 0; off >>= 1)
        total += __shfl_down(total, off, 64);
    __shared__ double wsum[4];
    int lane = threadIdx.x & 63;
    int wid  = threadIdx.x >> 6;
    if (lane == 0) wsum[wid] = total;
    __syncthreads();
    if (threadIdx.x == 0) {
        partials[blockIdx.x] = wsum[0] + wsum[1] + wsum[2] + wsum[3];
    }
}

__global__ __launch_bounds__(256) void finalize(
    const double* __restrict__ partials, float* __restrict__ out)
{
    // 256 threads, each sums NBLOCKS/256 = 8 slots, then reduce.
    double t = 0.0;
    for (int i = threadIdx.x; i < NBLOCKS; i += 256)
        t += partials[i];
    for (int off = 32; off > 0; off >>= 1)
        t += __shfl_down(t, off, 64);
    __shared__ double wsum[4];
    int lane = threadIdx.x & 63;
    int wid  = threadIdx.x >> 6;
    if (lane == 0) wsum[wid] = t;
    __syncthreads();
    if (threadIdx.x == 0)
        out[0] = (float)(wsum[0] + wsum[1] + wsum[2] + wsum[3]);
}

extern "C" void kernel_launch(void* const* d_in, const int* in_sizes, int n_in,
                              void* d_out, int out_size, void* d_ws, size_t ws_size,
                              hipStream_t stream) {
    const float* zs      = (const float*)d_in[0];
    const float* rzs     = (const float*)d_in[1];
    const float* pts     = (const float*)d_in[2];
    const float* best    = (const float*)d_in[3];
    const float* qy      = (const float*)d_in[4];
    const float* gts     = (const float*)d_in[5];
    const float* best_gt = (const float*)d_in[6];
    const int*   mapping = (const int*)d_in[7];

    double* partials = (double*)d_ws;  // 2048 doubles = 16 KB, written every call

    fused_loss<<<NBLOCKS, 256, 0, stream>>>(zs, rzs, pts, best, qy, gts, best_gt,
                                            mapping, partials);
    finalize<<<1, 256, 0, stream>>>(partials, (float*)d_out);
}